// Round 14
// baseline (183.552 us; speedup 1.0000x reference)
//
#include <hip/hip_runtime.h>
#include <hip/hip_bf16.h>
#include <math.h>

#define DD 64
#define NSLICE 64          // edge slices; per-slice edges = 12500
#define NMAXH4 12500       // u8 counters packed 4/word for N=50000 (50 KB LDS)

__device__ __forceinline__ int wave_incl_scan(int v, int lane) {
    #pragma unroll
    for (int d = 1; d < 64; d <<= 1) {
        int u = __shfl_up(v, d, 64);
        if (lane >= d) v += u;
    }
    return v;
}

// bf16 round-to-nearest-even (values finite; no NaN handling needed)
__device__ __forceinline__ unsigned bfr(float f) {
    unsigned u = __float_as_uint(f);
    return (u + 0x7FFFu + ((u >> 16) & 1u)) >> 16;
}
__device__ __forceinline__ unsigned packbf2(float lo, float hi) {
    return bfr(lo) | (bfr(hi) << 16);
}
__device__ __forceinline__ float bf2f(unsigned short h) {
    return __uint_as_float((unsigned)h << 16);
}

// ---------------- histogram: grid = (slice, which), u8 counts packed x4 ---
__global__ __launch_bounds__(256) void hist_kernel(
    const int* __restrict__ src, const int* __restrict__ dst,
    unsigned char* __restrict__ hist_o, unsigned char* __restrict__ hist_i,
    int E, int N)
{
    __shared__ unsigned int h[NMAXH4];
    int b = blockIdx.x, which = blockIdx.y, t = threadIdx.x;
    const int* col = which ? dst : src;
    int per = (E + NSLICE - 1) / NSLICE;
    int e0 = b * per, e1 = min(E, e0 + per);

    for (int j = t; j < NMAXH4; j += 256) h[j] = 0u;
    __syncthreads();

    int eV = e1 & ~3;
    const int4* c4 = (const int4*)col;
    for (int q = (e0 >> 2) + t; q < (eV >> 2); q += 256) {
        int4 v = c4[q];
        unsigned u;
        u = (unsigned)v.x; atomicAdd(&h[u >> 2], 1u << ((u & 3) * 8));
        u = (unsigned)v.y; atomicAdd(&h[u >> 2], 1u << ((u & 3) * 8));
        u = (unsigned)v.z; atomicAdd(&h[u >> 2], 1u << ((u & 3) * 8));
        u = (unsigned)v.w; atomicAdd(&h[u >> 2], 1u << ((u & 3) * 8));
    }
    for (int e = eV + t; e < e1; e += 256) {
        unsigned u = (unsigned)col[e];
        atomicAdd(&h[u >> 2], 1u << ((u & 3) * 8));
    }
    __syncthreads();

    // packed u32 writeout: word j holds counts for nodes 4j..4j+3
    unsigned* orow = (unsigned*)((which ? hist_i : hist_o) + (size_t)b * N);
    int nw = N >> 2;                     // 12500 for N=50000
    for (int j = t; j < nw; j += 256) orow[j] = h[j];
}

// ------ fused reduce + block-level scan + bf16 y = x*rs_odeg stream ------
// hist_i is now READ-ONLY (no per-slice prefix write-back: the atomic
// bucket no longer needs it).
__global__ __launch_bounds__(256) void reduce_scan_kernel(
    const unsigned char* __restrict__ hist_o, const unsigned char* __restrict__ hist_i,
    int* __restrict__ offs, const float* __restrict__ x,
    unsigned short* __restrict__ y,
    float* __restrict__ rs_ideg, int* __restrict__ bsum, int N)
{
    int t = threadIdx.x, lane = t & 63, wid = t >> 6;
    int d = blockIdx.x * 256 + t;
    int run_o = 0, run_i = 0;
    if (d < N) {
        #pragma unroll 8
        for (int b = 0; b < NSLICE; ++b) {
            run_o += hist_o[(size_t)b * N + d];
            run_i += hist_i[(size_t)b * N + d];
        }
    }
    int sv = wave_incl_scan(run_i, lane);
    __shared__ int ws[4], wso[4];
    __shared__ float sww[256];
    sww[t] = (d < N && run_o > 0) ? rsqrtf((float)run_o) : 0.0f;
    if (lane == 63) ws[wid] = sv;
    __syncthreads();
    if (t == 0) {
        int a = 0;
        for (int w = 0; w < 4; ++w) { wso[w] = a; a += ws[w]; }
        bsum[blockIdx.x] = a;
    }
    __syncthreads();
    if (d < N) {
        offs[d] = sv - run_i + wso[wid];
        rs_ideg[d] = (run_i > 0) ? rsqrtf((float)run_i) : 0.0f;
    }

    // coalesced y stream for rows [blockIdx*256, +256): w from LDS
    int r0 = blockIdx.x * 256;
    int nr = min(256, N - r0);
    if (nr <= 0) return;
    int tot = nr * 8;                     // uint4 chunks of 8 bf16
    for (int q = t; q < tot; q += 256) {
        int row = r0 + (q >> 3);
        int c8 = (q & 7) << 3;
        float w = sww[q >> 3];
        const float4 a = *(const float4*)&x[(size_t)row * DD + c8];
        const float4 b = *(const float4*)&x[(size_t)row * DD + c8 + 4];
        uint4 o;
        o.x = packbf2(a.x * w, a.y * w);
        o.y = packbf2(a.z * w, a.w * w);
        o.z = packbf2(b.x * w, b.y * w);
        o.w = packbf2(b.z * w, b.w * w);
        *(uint4*)&y[(size_t)row * DD + c8] = o;
    }
}

// ------ scan_add: offs += exclusive block prefix; also seed cur = offs ----
__global__ __launch_bounds__(256) void scan_add_kernel(
    int* __restrict__ offs, int* __restrict__ cur,
    const int* __restrict__ bsum, int n)
{
    __shared__ int wsum[4];
    int t = threadIdx.x, lane = t & 63, wid = t >> 6;
    int v = (t < blockIdx.x) ? bsum[t] : 0;    // nb <= 256
    #pragma unroll
    for (int dlt = 32; dlt >= 1; dlt >>= 1) v += __shfl_xor(v, dlt, 64);
    if (lane == 0) wsum[wid] = v;
    __syncthreads();
    int pre = wsum[0] + wsum[1] + wsum[2] + wsum[3];
    int i = blockIdx.x * 256 + t;
    if (i < n) {
        int f = offs[i] + pre;
        offs[i] = f;
        cur[i] = f;                       // atomic bucket counters
    }
}

// ---- bucket fill: single pass, global atomics on cur (L2-resident) ------
// Edge arrays read ONCE (6.4 MB vs 19.2 MB for the 3-segment variant);
// 800K atomicAdds over 50K counters (avg 16/addr, low contention).
// Within-node edge order becomes nondeterministic -- tolerance established
// (intra-slice order was already wave-schedule-dependent all session).
__global__ __launch_bounds__(256) void bucket_kernel(
    const int* __restrict__ src, const int* __restrict__ dst,
    int* __restrict__ cur, int* __restrict__ sorted_s, int E)
{
    int idx = blockIdx.x * 256 + threadIdx.x;
    int stride = gridDim.x * 256;
    int nv = E >> 2;
    const int4* s4 = (const int4*)src;
    const int4* d4 = (const int4*)dst;
    for (int q = idx; q < nv; q += stride) {
        int4 dv = d4[q];
        int4 sv = s4[q];
        sorted_s[atomicAdd(&cur[dv.x], 1)] = sv.x;
        sorted_s[atomicAdd(&cur[dv.y], 1)] = sv.y;
        sorted_s[atomicAdd(&cur[dv.z], 1)] = sv.z;
        sorted_s[atomicAdd(&cur[dv.w], 1)] = sv.w;
    }
    for (int e = (nv << 2) + idx; e < E; e += stride)
        sorted_s[atomicAdd(&cur[dst[e]], 1)] = src[e];
}

// macros for the pipelined gather (named scalars: no runtime-indexed arrays)
#define LDI8(A0,A1,A2,A3,A4,A5,A6,A7, base) \
    A0 = sorted_s[(base)+0]; A1 = sorted_s[(base)+1]; \
    A2 = sorted_s[(base)+2]; A3 = sorted_s[(base)+3]; \
    A4 = sorted_s[(base)+4]; A5 = sorted_s[(base)+5]; \
    A6 = sorted_s[(base)+6]; A7 = sorted_s[(base)+7];
#define LDR8(V0,V1,V2,V3,V4,V5,V6,V7, A0,A1,A2,A3,A4,A5,A6,A7) \
    V0 = *(const ushort4*)&y[(size_t)A0 * DD + coff]; \
    V1 = *(const ushort4*)&y[(size_t)A1 * DD + coff]; \
    V2 = *(const ushort4*)&y[(size_t)A2 * DD + coff]; \
    V3 = *(const ushort4*)&y[(size_t)A3 * DD + coff]; \
    V4 = *(const ushort4*)&y[(size_t)A4 * DD + coff]; \
    V5 = *(const ushort4*)&y[(size_t)A5 * DD + coff]; \
    V6 = *(const ushort4*)&y[(size_t)A6 * DD + coff]; \
    V7 = *(const ushort4*)&y[(size_t)A7 * DD + coff];
#define ACC1(V) \
    acc.x += bf2f(V.x); acc.y += bf2f(V.y); acc.z += bf2f(V.z); acc.w += bf2f(V.w);
#define ACC8(V0,V1,V2,V3,V4,V5,V6,V7) \
    ACC1(V0) ACC1(V1) ACC1(V2) ACC1(V3) ACC1(V4) ACC1(V5) ACC1(V6) ACC1(V7)

// ---- fused gather + FFN: 256 threads, 64 rows/block (grid 782), bf16 y ----
// Unchanged from round-13 (proven local optimum).
__global__ __launch_bounds__(256) void gather_ffn_kernel(
    const unsigned short* __restrict__ y,
    const int* __restrict__ sorted_s,
    const int* __restrict__ offs,
    const float* __restrict__ rs_ideg,
    const float* __restrict__ w1, const float* __restrict__ b1,
    const float* __restrict__ w2, const float* __restrict__ b2,
    float* __restrict__ out, int N, int E)
{
    __shared__ float sW[4096];          // W1 during GEMM1, W2 during GEMM2
    __shared__ float sT[64 * 68];

    int t = threadIdx.x;
    int row0 = blockIdx.x * 64;

    // stage W1 -> LDS; load W2 -> regs (written to LDS after GEMM1)
    const float4* w1v = (const float4*)w1;
    const float4* w2v = (const float4*)w2;
    float4 w2r[4];
    #pragma unroll
    for (int q = 0; q < 4; ++q) {
        ((float4*)sW)[t + q * 256] = w1v[t + q * 256];
        w2r[q] = w2v[t + q * 256];
    }

    // ---- gather phase: 16-lane subgroup per node, 4 nodes per subgroup ----
    int g = t >> 4, l16 = t & 15;
    int coff = l16 << 2;                // column index (4 cols = 8 B per lane)
    for (int r = g; r < 64; r += 16) {
        int d = row0 + r;
        float4 acc = make_float4(0.f, 0.f, 0.f, 0.f);
        if (d < N) {
            int beg = offs[d];
            int end = (d + 1 < N) ? offs[d + 1] : E;
            float nd = rs_ideg[d];
            int cnt = end - beg;
            int nch = cnt >> 3;

            int ia0, ia1, ia2, ia3, ia4, ia5, ia6, ia7;
            int ib0, ib1, ib2, ib3, ib4, ib5, ib6, ib7;
            ushort4 va0, va1, va2, va3, va4, va5, va6, va7;
            ushort4 vb0, vb1, vb2, vb3, vb4, vb5, vb6, vb7;

            if (nch > 0) {
                LDI8(ia0,ia1,ia2,ia3,ia4,ia5,ia6,ia7, beg)
                LDR8(va0,va1,va2,va3,va4,va5,va6,va7, ia0,ia1,ia2,ia3,ia4,ia5,ia6,ia7)
                if (nch > 1) { LDI8(ib0,ib1,ib2,ib3,ib4,ib5,ib6,ib7, beg + 8) }
                int c = 0, k = beg;
                for (; c + 2 <= nch; c += 2) {
                    // rows of chunk c+1 (younger than va's loads)
                    LDR8(vb0,vb1,vb2,vb3,vb4,vb5,vb6,vb7, ib0,ib1,ib2,ib3,ib4,ib5,ib6,ib7)
                    if (c + 2 < nch) { LDI8(ia0,ia1,ia2,ia3,ia4,ia5,ia6,ia7, k + 16) }
                    ACC8(va0,va1,va2,va3,va4,va5,va6,va7)   // waits on va only
                    k += 8;
                    if (c + 2 < nch) {
                        LDR8(va0,va1,va2,va3,va4,va5,va6,va7, ia0,ia1,ia2,ia3,ia4,ia5,ia6,ia7)
                        if (c + 3 < nch) { LDI8(ib0,ib1,ib2,ib3,ib4,ib5,ib6,ib7, k + 16) }
                    }
                    ACC8(vb0,vb1,vb2,vb3,vb4,vb5,vb6,vb7)
                    k += 8;
                }
                if (c < nch) {          // odd chunk count: last chunk sits in va
                    ACC8(va0,va1,va2,va3,va4,va5,va6,va7)
                }
            }
            // masked one-shot tail: rr in [0,7]
            int kt = beg + (nch << 3);
            int rr = end - kt;
            if (rr > 0) {
                int lastv = rr - 1;
                int t0 = sorted_s[kt];
                int t1 = sorted_s[kt + ((1 < rr) ? 1 : lastv)];
                int t2 = sorted_s[kt + ((2 < rr) ? 2 : lastv)];
                int t3 = sorted_s[kt + ((3 < rr) ? 3 : lastv)];
                int t4 = sorted_s[kt + ((4 < rr) ? 4 : lastv)];
                int t5 = sorted_s[kt + ((5 < rr) ? 5 : lastv)];
                int t6 = sorted_s[kt + ((6 < rr) ? 6 : lastv)];
                int t7 = sorted_s[kt + ((7 < rr) ? 7 : lastv)];
                ushort4 w0, w1q, w2q, w3, w4, w5, w6, w7;
                LDR8(w0,w1q,w2q,w3,w4,w5,w6,w7, t0,t1,t2,t3,t4,t5,t6,t7)
                ACC1(w0)                                     // j=0 always valid
                acc.x += (1 < rr) ? bf2f(w1q.x) : 0.0f; acc.y += (1 < rr) ? bf2f(w1q.y) : 0.0f;
                acc.z += (1 < rr) ? bf2f(w1q.z) : 0.0f; acc.w += (1 < rr) ? bf2f(w1q.w) : 0.0f;
                acc.x += (2 < rr) ? bf2f(w2q.x) : 0.0f; acc.y += (2 < rr) ? bf2f(w2q.y) : 0.0f;
                acc.z += (2 < rr) ? bf2f(w2q.z) : 0.0f; acc.w += (2 < rr) ? bf2f(w2q.w) : 0.0f;
                acc.x += (3 < rr) ? bf2f(w3.x) : 0.0f; acc.y += (3 < rr) ? bf2f(w3.y) : 0.0f;
                acc.z += (3 < rr) ? bf2f(w3.z) : 0.0f; acc.w += (3 < rr) ? bf2f(w3.w) : 0.0f;
                acc.x += (4 < rr) ? bf2f(w4.x) : 0.0f; acc.y += (4 < rr) ? bf2f(w4.y) : 0.0f;
                acc.z += (4 < rr) ? bf2f(w4.z) : 0.0f; acc.w += (4 < rr) ? bf2f(w4.w) : 0.0f;
                acc.x += (5 < rr) ? bf2f(w5.x) : 0.0f; acc.y += (5 < rr) ? bf2f(w5.y) : 0.0f;
                acc.z += (5 < rr) ? bf2f(w5.z) : 0.0f; acc.w += (5 < rr) ? bf2f(w5.w) : 0.0f;
                acc.x += (6 < rr) ? bf2f(w6.x) : 0.0f; acc.y += (6 < rr) ? bf2f(w6.y) : 0.0f;
                acc.z += (6 < rr) ? bf2f(w6.z) : 0.0f; acc.w += (6 < rr) ? bf2f(w6.w) : 0.0f;
                acc.x += (7 < rr) ? bf2f(w7.x) : 0.0f; acc.y += (7 < rr) ? bf2f(w7.y) : 0.0f;
                acc.z += (7 < rr) ? bf2f(w7.z) : 0.0f; acc.w += (7 < rr) ? bf2f(w7.w) : 0.0f;
            }
            acc.x *= nd; acc.y *= nd; acc.z *= nd; acc.w *= nd;
        }
        *(float4*)&sT[r * 68 + coff] = acc;
    }
    __syncthreads();

    // ---- FFN phase: slot = t>>3 (0..31) covers rows slot, slot+32 ----
    int slot = t >> 3;
    int cb = (t & 7) << 3;

    float a[2][8];
    #pragma unroll
    for (int j = 0; j < 8; ++j) {
        float bv = b1[cb + j];
        a[0][j] = bv; a[1][j] = bv;
    }
    #pragma unroll 2
    for (int k = 0; k < 64; ++k) {
        float rv0 = sT[(slot      ) * 68 + k];
        float rv1 = sT[(slot + 32 ) * 68 + k];
        #pragma unroll
        for (int q = 0; q < 2; ++q) {
            float4 w = *(const float4*)&sW[k * 64 + cb + (q << 2)];
            a[0][q*4+0] = fmaf(rv0, w.x, a[0][q*4+0]); a[1][q*4+0] = fmaf(rv1, w.x, a[1][q*4+0]);
            a[0][q*4+1] = fmaf(rv0, w.y, a[0][q*4+1]); a[1][q*4+1] = fmaf(rv1, w.y, a[1][q*4+1]);
            a[0][q*4+2] = fmaf(rv0, w.z, a[0][q*4+2]); a[1][q*4+2] = fmaf(rv1, w.z, a[1][q*4+2]);
            a[0][q*4+3] = fmaf(rv0, w.w, a[0][q*4+3]); a[1][q*4+3] = fmaf(rv1, w.w, a[1][q*4+3]);
        }
    }
    #pragma unroll
    for (int i = 0; i < 2; ++i)
        #pragma unroll
        for (int j = 0; j < 8; ++j) {
            float v = a[i][j];
            a[i][j] = 0.5f * v * (1.0f + erff(v * 0.70710678118654752f));
        }
    __syncthreads();   // all GEMM1 reads of sT AND sW complete before overwrite
    #pragma unroll
    for (int i = 0; i < 2; ++i)
        #pragma unroll
        for (int q = 0; q < 2; ++q)
            *(float4*)&sT[(slot + 32 * i) * 68 + cb + (q << 2)] =
                make_float4(a[i][q*4+0], a[i][q*4+1], a[i][q*4+2], a[i][q*4+3]);
    #pragma unroll
    for (int q = 0; q < 4; ++q)
        ((float4*)sW)[t + q * 256] = w2r[q];     // W2 into the shared buffer
    __syncthreads();

    float o[2][8];
    #pragma unroll
    for (int j = 0; j < 8; ++j) {
        float bv = b2[cb + j];
        o[0][j] = bv; o[1][j] = bv;
    }
    #pragma unroll 2
    for (int k = 0; k < 64; ++k) {
        float hv0 = sT[(slot      ) * 68 + k];
        float hv1 = sT[(slot + 32 ) * 68 + k];
        #pragma unroll
        for (int q = 0; q < 2; ++q) {
            float4 w = *(const float4*)&sW[k * 64 + cb + (q << 2)];
            o[0][q*4+0] = fmaf(hv0, w.x, o[0][q*4+0]); o[1][q*4+0] = fmaf(hv1, w.x, o[1][q*4+0]);
            o[0][q*4+1] = fmaf(hv0, w.y, o[0][q*4+1]); o[1][q*4+1] = fmaf(hv1, w.y, o[1][q*4+1]);
            o[0][q*4+2] = fmaf(hv0, w.z, o[0][q*4+2]); o[1][q*4+2] = fmaf(hv1, w.z, o[1][q*4+2]);
            o[0][q*4+3] = fmaf(hv0, w.w, o[0][q*4+3]); o[1][q*4+3] = fmaf(hv1, w.w, o[1][q*4+3]);
        }
    }
    // direct store: thread covers rows slot, slot+32, cols cb..cb+7
    #pragma unroll
    for (int i = 0; i < 2; ++i) {
        int row = row0 + slot + 32 * i;
        if (row < N) {
            *(float4*)&out[(size_t)row * DD + cb    ] =
                make_float4(o[i][0], o[i][1], o[i][2], o[i][3]);
            *(float4*)&out[(size_t)row * DD + cb + 4] =
                make_float4(o[i][4], o[i][5], o[i][6], o[i][7]);
        }
    }
}

extern "C" void kernel_launch(void* const* d_in, const int* in_sizes, int n_in,
                              void* d_out, int out_size, void* d_ws, size_t ws_size,
                              hipStream_t stream)
{
    const float* x    = (const float*)d_in[0];
    const int*   esrc = (const int*)d_in[1];
    const int*   edst = (const int*)d_in[2];
    const float* w1   = (const float*)d_in[3];
    const float* b1   = (const float*)d_in[4];
    const float* w2   = (const float*)d_in[5];
    const float* b2   = (const float*)d_in[6];
    float* out = (float*)d_out;

    int N = in_sizes[0] / DD;   // 50000
    int E = in_sizes[1];        // 800000
    int nb = (N + 255) / 256;   // 196

    // workspace layout (d_ws is >=256B aligned)
    unsigned short* y          = (unsigned short*)d_ws;              // N*DD bf16
    int*            sorted_s   = (int*)(y + (size_t)N * DD);         // E
    int*            offs       = sorted_s + E;                       // N
    int*            cur        = offs + N;                           // N
    float*          rs_ideg    = (float*)(cur + N);                  // N
    int*            bsum       = (int*)(rs_ideg + N);                // 256
    unsigned char*  hist_o     = (unsigned char*)(bsum + 256);       // NSLICE*N u8
    unsigned char*  hist_i     = hist_o + (size_t)NSLICE * N;        // NSLICE*N u8

    hist_kernel<<<dim3(NSLICE, 2), 256, 0, stream>>>(esrc, edst, hist_o, hist_i, E, N);
    reduce_scan_kernel<<<nb, 256, 0, stream>>>(hist_o, hist_i, offs, x, y, rs_ideg, bsum, N);
    scan_add_kernel<<<nb, 256, 0, stream>>>(offs, cur, bsum, N);
    bucket_kernel<<<512, 256, 0, stream>>>(esrc, edst, cur, sorted_s, E);
    gather_ffn_kernel<<<(N + 63) / 64, 256, 0, stream>>>(y, sorted_s, offs, rs_ideg,
                                                         w1, b1, w2, b2, out, N, E);
}

// Round 15
// 159.071 us; speedup vs baseline: 1.1539x; 1.1539x over previous
//
#include <hip/hip_runtime.h>
#include <hip/hip_bf16.h>
#include <math.h>

#define DD 64
#define NSLICE 64          // edge slices; per-slice edges = 12500
#define NMAXH4 12500       // u8 counters packed 4/word for N=50000 (50 KB LDS)

__device__ __forceinline__ int wave_incl_scan(int v, int lane) {
    #pragma unroll
    for (int d = 1; d < 64; d <<= 1) {
        int u = __shfl_up(v, d, 64);
        if (lane >= d) v += u;
    }
    return v;
}

// bf16 round-to-nearest-even (values finite; no NaN handling needed)
__device__ __forceinline__ unsigned bfr(float f) {
    unsigned u = __float_as_uint(f);
    return (u + 0x7FFFu + ((u >> 16) & 1u)) >> 16;
}
__device__ __forceinline__ unsigned packbf2(float lo, float hi) {
    return bfr(lo) | (bfr(hi) << 16);
}
__device__ __forceinline__ float bf2f(unsigned short h) {
    return __uint_as_float((unsigned)h << 16);
}

// ---------------- histogram: grid = (slice, which), u8 counts packed x4 ---
__global__ __launch_bounds__(256) void hist_kernel(
    const int* __restrict__ src, const int* __restrict__ dst,
    unsigned char* __restrict__ hist_o, unsigned char* __restrict__ hist_i,
    int E, int N)
{
    __shared__ unsigned int h[NMAXH4];
    int b = blockIdx.x, which = blockIdx.y, t = threadIdx.x;
    const int* col = which ? dst : src;
    int per = (E + NSLICE - 1) / NSLICE;
    int e0 = b * per, e1 = min(E, e0 + per);

    for (int j = t; j < NMAXH4; j += 256) h[j] = 0u;
    __syncthreads();

    int eV = e1 & ~3;
    const int4* c4 = (const int4*)col;
    for (int q = (e0 >> 2) + t; q < (eV >> 2); q += 256) {
        int4 v = c4[q];
        unsigned u;
        u = (unsigned)v.x; atomicAdd(&h[u >> 2], 1u << ((u & 3) * 8));
        u = (unsigned)v.y; atomicAdd(&h[u >> 2], 1u << ((u & 3) * 8));
        u = (unsigned)v.z; atomicAdd(&h[u >> 2], 1u << ((u & 3) * 8));
        u = (unsigned)v.w; atomicAdd(&h[u >> 2], 1u << ((u & 3) * 8));
    }
    for (int e = eV + t; e < e1; e += 256) {
        unsigned u = (unsigned)col[e];
        atomicAdd(&h[u >> 2], 1u << ((u & 3) * 8));
    }
    __syncthreads();

    // packed u32 writeout: word j holds counts for nodes 4j..4j+3
    unsigned* orow = (unsigned*)((which ? hist_i : hist_o) + (size_t)b * N);
    int nw = N >> 2;                     // 12500 for N=50000
    for (int j = t; j < nw; j += 256) orow[j] = h[j];
}

// ------ fused reduce + block-level scan + bf16 y = x*rs_odeg stream ------
__global__ __launch_bounds__(256) void reduce_scan_kernel(
    const unsigned char* __restrict__ hist_o, unsigned char* __restrict__ hist_i,
    int* __restrict__ offs, const float* __restrict__ x,
    unsigned short* __restrict__ y,
    float* __restrict__ rs_ideg, int* __restrict__ bsum, int N)
{
    int t = threadIdx.x, lane = t & 63, wid = t >> 6;
    int d = blockIdx.x * 256 + t;
    int run_o = 0, run_i = 0;
    if (d < N) {
        #pragma unroll 8
        for (int b = 0; b < NSLICE; ++b) {
            run_o += hist_o[(size_t)b * N + d];
            int tv = hist_i[(size_t)b * N + d];
            hist_i[(size_t)b * N + d] = (unsigned char)run_i;  // excl prefix over slices
            run_i += tv;
        }
    }
    int sv = wave_incl_scan(run_i, lane);
    __shared__ int ws[4], wso[4];
    __shared__ float sww[256];
    sww[t] = (d < N && run_o > 0) ? rsqrtf((float)run_o) : 0.0f;
    if (lane == 63) ws[wid] = sv;
    __syncthreads();
    if (t == 0) {
        int a = 0;
        for (int w = 0; w < 4; ++w) { wso[w] = a; a += ws[w]; }
        bsum[blockIdx.x] = a;
    }
    __syncthreads();
    if (d < N) {
        offs[d] = sv - run_i + wso[wid];
        rs_ideg[d] = (run_i > 0) ? rsqrtf((float)run_i) : 0.0f;
    }

    // coalesced y stream for rows [blockIdx*256, +256): w from LDS
    int r0 = blockIdx.x * 256;
    int nr = min(256, N - r0);
    if (nr <= 0) return;
    int tot = nr * 8;                     // uint4 chunks of 8 bf16
    for (int q = t; q < tot; q += 256) {
        int row = r0 + (q >> 3);
        int c8 = (q & 7) << 3;
        float w = sww[q >> 3];
        const float4 a = *(const float4*)&x[(size_t)row * DD + c8];
        const float4 b = *(const float4*)&x[(size_t)row * DD + c8 + 4];
        uint4 o;
        o.x = packbf2(a.x * w, a.y * w);
        o.y = packbf2(a.z * w, a.w * w);
        o.z = packbf2(b.x * w, b.y * w);
        o.w = packbf2(b.z * w, b.w * w);
        *(uint4*)&y[(size_t)row * DD + c8] = o;
    }
}

// ------ scan_add: offs += exclusive block prefix ------
__global__ __launch_bounds__(256) void scan_add_kernel(
    int* __restrict__ offs, const int* __restrict__ bsum, int n)
{
    __shared__ int wsum[4];
    int t = threadIdx.x, lane = t & 63, wid = t >> 6;
    int v = (t < blockIdx.x) ? bsum[t] : 0;    // nb <= 256
    #pragma unroll
    for (int dlt = 32; dlt >= 1; dlt >>= 1) v += __shfl_xor(v, dlt, 64);
    if (lane == 0) wsum[wid] = v;
    __syncthreads();
    int pre = wsum[0] + wsum[1] + wsum[2] + wsum[3];
    int i = blockIdx.x * 256 + t;
    if (i < n) offs[i] += pre;
}

// ---- bucket fill: LDS-segmented, SEG=25000 (100 KB) -> 2 segments -------
// Edge arrays read 2x (12.8 MB) instead of 3x (19.2 MB). Placement logic
// identical to the measured round-13 structure, only segment size changed.
#define SEG 25000
#define NSEG 2
__global__ __launch_bounds__(256) void bucket_kernel(
    const int* __restrict__ src, const int* __restrict__ dst,
    const int* __restrict__ offs, const unsigned char* __restrict__ hist_i,
    int* __restrict__ sorted_s, int E, int N)
{
    __shared__ int cur[SEG];
    int b = blockIdx.x, s = blockIdx.y, t = threadIdx.x;
    int per = (E + NSLICE - 1) / NSLICE;
    int e0 = b * per, e1 = min(E, e0 + per);
    int base = s * SEG;
    int segn = min(SEG, N - base);
    if (segn <= 0) return;

    for (int j = t; j < segn; j += 256)
        cur[j] = offs[base + j] + (int)hist_i[(size_t)b * N + base + j];
    __syncthreads();

    int eV = e1 & ~3;
    const int4* s4 = (const int4*)src;
    const int4* d4 = (const int4*)dst;
    for (int q = (e0 >> 2) + t; q < (eV >> 2); q += 256) {
        int4 dv = d4[q];
        int4 sv = s4[q];
        unsigned ux = (unsigned)(dv.x - base);
        unsigned uy = (unsigned)(dv.y - base);
        unsigned uz = (unsigned)(dv.z - base);
        unsigned uw = (unsigned)(dv.w - base);
        if (ux < (unsigned)segn) sorted_s[atomicAdd(&cur[ux], 1)] = sv.x;
        if (uy < (unsigned)segn) sorted_s[atomicAdd(&cur[uy], 1)] = sv.y;
        if (uz < (unsigned)segn) sorted_s[atomicAdd(&cur[uz], 1)] = sv.z;
        if (uw < (unsigned)segn) sorted_s[atomicAdd(&cur[uw], 1)] = sv.w;
    }
    for (int e = eV + t; e < e1; e += 256) {
        unsigned u = (unsigned)(dst[e] - base);
        if (u < (unsigned)segn)
            sorted_s[atomicAdd(&cur[u], 1)] = src[e];
    }
}

// macros for the pipelined gather (named scalars: no runtime-indexed arrays)
#define LDI8(A0,A1,A2,A3,A4,A5,A6,A7, base) \
    A0 = sorted_s[(base)+0]; A1 = sorted_s[(base)+1]; \
    A2 = sorted_s[(base)+2]; A3 = sorted_s[(base)+3]; \
    A4 = sorted_s[(base)+4]; A5 = sorted_s[(base)+5]; \
    A6 = sorted_s[(base)+6]; A7 = sorted_s[(base)+7];
#define LDR8(V0,V1,V2,V3,V4,V5,V6,V7, A0,A1,A2,A3,A4,A5,A6,A7) \
    V0 = *(const ushort4*)&y[(size_t)A0 * DD + coff]; \
    V1 = *(const ushort4*)&y[(size_t)A1 * DD + coff]; \
    V2 = *(const ushort4*)&y[(size_t)A2 * DD + coff]; \
    V3 = *(const ushort4*)&y[(size_t)A3 * DD + coff]; \
    V4 = *(const ushort4*)&y[(size_t)A4 * DD + coff]; \
    V5 = *(const ushort4*)&y[(size_t)A5 * DD + coff]; \
    V6 = *(const ushort4*)&y[(size_t)A6 * DD + coff]; \
    V7 = *(const ushort4*)&y[(size_t)A7 * DD + coff];
#define ACC1(V) \
    acc.x += bf2f(V.x); acc.y += bf2f(V.y); acc.z += bf2f(V.z); acc.w += bf2f(V.w);
#define ACC8(V0,V1,V2,V3,V4,V5,V6,V7) \
    ACC1(V0) ACC1(V1) ACC1(V2) ACC1(V3) ACC1(V4) ACC1(V5) ACC1(V6) ACC1(V7)

// ---- fused gather + FFN: 256 threads, 64 rows/block (grid 782), bf16 y ----
// Unchanged from round-13 (proven local optimum).
__global__ __launch_bounds__(256) void gather_ffn_kernel(
    const unsigned short* __restrict__ y,
    const int* __restrict__ sorted_s,
    const int* __restrict__ offs,
    const float* __restrict__ rs_ideg,
    const float* __restrict__ w1, const float* __restrict__ b1,
    const float* __restrict__ w2, const float* __restrict__ b2,
    float* __restrict__ out, int N, int E)
{
    __shared__ float sW[4096];          // W1 during GEMM1, W2 during GEMM2
    __shared__ float sT[64 * 68];

    int t = threadIdx.x;
    int row0 = blockIdx.x * 64;

    // stage W1 -> LDS; load W2 -> regs (written to LDS after GEMM1)
    const float4* w1v = (const float4*)w1;
    const float4* w2v = (const float4*)w2;
    float4 w2r[4];
    #pragma unroll
    for (int q = 0; q < 4; ++q) {
        ((float4*)sW)[t + q * 256] = w1v[t + q * 256];
        w2r[q] = w2v[t + q * 256];
    }

    // ---- gather phase: 16-lane subgroup per node, 4 nodes per subgroup ----
    int g = t >> 4, l16 = t & 15;
    int coff = l16 << 2;                // column index (4 cols = 8 B per lane)
    for (int r = g; r < 64; r += 16) {
        int d = row0 + r;
        float4 acc = make_float4(0.f, 0.f, 0.f, 0.f);
        if (d < N) {
            int beg = offs[d];
            int end = (d + 1 < N) ? offs[d + 1] : E;
            float nd = rs_ideg[d];
            int cnt = end - beg;
            int nch = cnt >> 3;

            int ia0, ia1, ia2, ia3, ia4, ia5, ia6, ia7;
            int ib0, ib1, ib2, ib3, ib4, ib5, ib6, ib7;
            ushort4 va0, va1, va2, va3, va4, va5, va6, va7;
            ushort4 vb0, vb1, vb2, vb3, vb4, vb5, vb6, vb7;

            if (nch > 0) {
                LDI8(ia0,ia1,ia2,ia3,ia4,ia5,ia6,ia7, beg)
                LDR8(va0,va1,va2,va3,va4,va5,va6,va7, ia0,ia1,ia2,ia3,ia4,ia5,ia6,ia7)
                if (nch > 1) { LDI8(ib0,ib1,ib2,ib3,ib4,ib5,ib6,ib7, beg + 8) }
                int c = 0, k = beg;
                for (; c + 2 <= nch; c += 2) {
                    // rows of chunk c+1 (younger than va's loads)
                    LDR8(vb0,vb1,vb2,vb3,vb4,vb5,vb6,vb7, ib0,ib1,ib2,ib3,ib4,ib5,ib6,ib7)
                    if (c + 2 < nch) { LDI8(ia0,ia1,ia2,ia3,ia4,ia5,ia6,ia7, k + 16) }
                    ACC8(va0,va1,va2,va3,va4,va5,va6,va7)   // waits on va only
                    k += 8;
                    if (c + 2 < nch) {
                        LDR8(va0,va1,va2,va3,va4,va5,va6,va7, ia0,ia1,ia2,ia3,ia4,ia5,ia6,ia7)
                        if (c + 3 < nch) { LDI8(ib0,ib1,ib2,ib3,ib4,ib5,ib6,ib7, k + 16) }
                    }
                    ACC8(vb0,vb1,vb2,vb3,vb4,vb5,vb6,vb7)
                    k += 8;
                }
                if (c < nch) {          // odd chunk count: last chunk sits in va
                    ACC8(va0,va1,va2,va3,va4,va5,va6,va7)
                }
            }
            // masked one-shot tail: rr in [0,7]
            int kt = beg + (nch << 3);
            int rr = end - kt;
            if (rr > 0) {
                int lastv = rr - 1;
                int t0 = sorted_s[kt];
                int t1 = sorted_s[kt + ((1 < rr) ? 1 : lastv)];
                int t2 = sorted_s[kt + ((2 < rr) ? 2 : lastv)];
                int t3 = sorted_s[kt + ((3 < rr) ? 3 : lastv)];
                int t4 = sorted_s[kt + ((4 < rr) ? 4 : lastv)];
                int t5 = sorted_s[kt + ((5 < rr) ? 5 : lastv)];
                int t6 = sorted_s[kt + ((6 < rr) ? 6 : lastv)];
                int t7 = sorted_s[kt + ((7 < rr) ? 7 : lastv)];
                ushort4 w0, w1q, w2q, w3, w4, w5, w6, w7;
                LDR8(w0,w1q,w2q,w3,w4,w5,w6,w7, t0,t1,t2,t3,t4,t5,t6,t7)
                ACC1(w0)                                     // j=0 always valid
                acc.x += (1 < rr) ? bf2f(w1q.x) : 0.0f; acc.y += (1 < rr) ? bf2f(w1q.y) : 0.0f;
                acc.z += (1 < rr) ? bf2f(w1q.z) : 0.0f; acc.w += (1 < rr) ? bf2f(w1q.w) : 0.0f;
                acc.x += (2 < rr) ? bf2f(w2q.x) : 0.0f; acc.y += (2 < rr) ? bf2f(w2q.y) : 0.0f;
                acc.z += (2 < rr) ? bf2f(w2q.z) : 0.0f; acc.w += (2 < rr) ? bf2f(w2q.w) : 0.0f;
                acc.x += (3 < rr) ? bf2f(w3.x) : 0.0f; acc.y += (3 < rr) ? bf2f(w3.y) : 0.0f;
                acc.z += (3 < rr) ? bf2f(w3.z) : 0.0f; acc.w += (3 < rr) ? bf2f(w3.w) : 0.0f;
                acc.x += (4 < rr) ? bf2f(w4.x) : 0.0f; acc.y += (4 < rr) ? bf2f(w4.y) : 0.0f;
                acc.z += (4 < rr) ? bf2f(w4.z) : 0.0f; acc.w += (4 < rr) ? bf2f(w4.w) : 0.0f;
                acc.x += (5 < rr) ? bf2f(w5.x) : 0.0f; acc.y += (5 < rr) ? bf2f(w5.y) : 0.0f;
                acc.z += (5 < rr) ? bf2f(w5.z) : 0.0f; acc.w += (5 < rr) ? bf2f(w5.w) : 0.0f;
                acc.x += (6 < rr) ? bf2f(w6.x) : 0.0f; acc.y += (6 < rr) ? bf2f(w6.y) : 0.0f;
                acc.z += (6 < rr) ? bf2f(w6.z) : 0.0f; acc.w += (6 < rr) ? bf2f(w6.w) : 0.0f;
                acc.x += (7 < rr) ? bf2f(w7.x) : 0.0f; acc.y += (7 < rr) ? bf2f(w7.y) : 0.0f;
                acc.z += (7 < rr) ? bf2f(w7.z) : 0.0f; acc.w += (7 < rr) ? bf2f(w7.w) : 0.0f;
            }
            acc.x *= nd; acc.y *= nd; acc.z *= nd; acc.w *= nd;
        }
        *(float4*)&sT[r * 68 + coff] = acc;
    }
    __syncthreads();

    // ---- FFN phase: slot = t>>3 (0..31) covers rows slot, slot+32 ----
    int slot = t >> 3;
    int cb = (t & 7) << 3;

    float a[2][8];
    #pragma unroll
    for (int j = 0; j < 8; ++j) {
        float bv = b1[cb + j];
        a[0][j] = bv; a[1][j] = bv;
    }
    #pragma unroll 2
    for (int k = 0; k < 64; ++k) {
        float rv0 = sT[(slot      ) * 68 + k];
        float rv1 = sT[(slot + 32 ) * 68 + k];
        #pragma unroll
        for (int q = 0; q < 2; ++q) {
            float4 w = *(const float4*)&sW[k * 64 + cb + (q << 2)];
            a[0][q*4+0] = fmaf(rv0, w.x, a[0][q*4+0]); a[1][q*4+0] = fmaf(rv1, w.x, a[1][q*4+0]);
            a[0][q*4+1] = fmaf(rv0, w.y, a[0][q*4+1]); a[1][q*4+1] = fmaf(rv1, w.y, a[1][q*4+1]);
            a[0][q*4+2] = fmaf(rv0, w.z, a[0][q*4+2]); a[1][q*4+2] = fmaf(rv1, w.z, a[1][q*4+2]);
            a[0][q*4+3] = fmaf(rv0, w.w, a[0][q*4+3]); a[1][q*4+3] = fmaf(rv1, w.w, a[1][q*4+3]);
        }
    }
    #pragma unroll
    for (int i = 0; i < 2; ++i)
        #pragma unroll
        for (int j = 0; j < 8; ++j) {
            float v = a[i][j];
            a[i][j] = 0.5f * v * (1.0f + erff(v * 0.70710678118654752f));
        }
    __syncthreads();   // all GEMM1 reads of sT AND sW complete before overwrite
    #pragma unroll
    for (int i = 0; i < 2; ++i)
        #pragma unroll
        for (int q = 0; q < 2; ++q)
            *(float4*)&sT[(slot + 32 * i) * 68 + cb + (q << 2)] =
                make_float4(a[i][q*4+0], a[i][q*4+1], a[i][q*4+2], a[i][q*4+3]);
    #pragma unroll
    for (int q = 0; q < 4; ++q)
        ((float4*)sW)[t + q * 256] = w2r[q];     // W2 into the shared buffer
    __syncthreads();

    float o[2][8];
    #pragma unroll
    for (int j = 0; j < 8; ++j) {
        float bv = b2[cb + j];
        o[0][j] = bv; o[1][j] = bv;
    }
    #pragma unroll 2
    for (int k = 0; k < 64; ++k) {
        float hv0 = sT[(slot      ) * 68 + k];
        float hv1 = sT[(slot + 32 ) * 68 + k];
        #pragma unroll
        for (int q = 0; q < 2; ++q) {
            float4 w = *(const float4*)&sW[k * 64 + cb + (q << 2)];
            o[0][q*4+0] = fmaf(hv0, w.x, o[0][q*4+0]); o[1][q*4+0] = fmaf(hv1, w.x, o[1][q*4+0]);
            o[0][q*4+1] = fmaf(hv0, w.y, o[0][q*4+1]); o[1][q*4+1] = fmaf(hv1, w.y, o[1][q*4+1]);
            o[0][q*4+2] = fmaf(hv0, w.z, o[0][q*4+2]); o[1][q*4+2] = fmaf(hv1, w.z, o[1][q*4+2]);
            o[0][q*4+3] = fmaf(hv0, w.w, o[0][q*4+3]); o[1][q*4+3] = fmaf(hv1, w.w, o[1][q*4+3]);
        }
    }
    // direct store: thread covers rows slot, slot+32, cols cb..cb+7
    #pragma unroll
    for (int i = 0; i < 2; ++i) {
        int row = row0 + slot + 32 * i;
        if (row < N) {
            *(float4*)&out[(size_t)row * DD + cb    ] =
                make_float4(o[i][0], o[i][1], o[i][2], o[i][3]);
            *(float4*)&out[(size_t)row * DD + cb + 4] =
                make_float4(o[i][4], o[i][5], o[i][6], o[i][7]);
        }
    }
}

extern "C" void kernel_launch(void* const* d_in, const int* in_sizes, int n_in,
                              void* d_out, int out_size, void* d_ws, size_t ws_size,
                              hipStream_t stream)
{
    const float* x    = (const float*)d_in[0];
    const int*   esrc = (const int*)d_in[1];
    const int*   edst = (const int*)d_in[2];
    const float* w1   = (const float*)d_in[3];
    const float* b1   = (const float*)d_in[4];
    const float* w2   = (const float*)d_in[5];
    const float* b2   = (const float*)d_in[6];
    float* out = (float*)d_out;

    int N = in_sizes[0] / DD;   // 50000
    int E = in_sizes[1];        // 800000
    int nb = (N + 255) / 256;   // 196

    // workspace layout (d_ws is >=256B aligned)
    unsigned short* y          = (unsigned short*)d_ws;              // N*DD bf16
    int*            sorted_s   = (int*)(y + (size_t)N * DD);         // E
    int*            offs       = sorted_s + E;                       // N
    float*          rs_ideg    = (float*)(offs + N);                 // N
    int*            bsum       = (int*)(rs_ideg + N);                // 256
    unsigned char*  hist_o     = (unsigned char*)(bsum + 256);       // NSLICE*N u8
    unsigned char*  hist_i     = hist_o + (size_t)NSLICE * N;        // NSLICE*N u8

    hist_kernel<<<dim3(NSLICE, 2), 256, 0, stream>>>(esrc, edst, hist_o, hist_i, E, N);
    reduce_scan_kernel<<<nb, 256, 0, stream>>>(hist_o, hist_i, offs, x, y, rs_ideg, bsum, N);
    scan_add_kernel<<<nb, 256, 0, stream>>>(offs, bsum, N);
    bucket_kernel<<<dim3(NSLICE, NSEG), 256, 0, stream>>>(esrc, edst, offs, hist_i, sorted_s, E, N);
    gather_ffn_kernel<<<(N + 63) / 64, 256, 0, stream>>>(y, sorted_s, offs, rs_ideg,
                                                         w1, b1, w2, b2, out, N, E);
}

// Round 16
// 152.249 us; speedup vs baseline: 1.2056x; 1.0448x over previous
//
#include <hip/hip_runtime.h>
#include <hip/hip_bf16.h>
#include <math.h>

#define DD 64
#define NSLICE 64          // edge slices; per-slice edges = 12500
#define NMAXH4 12500       // u8 counters packed 4/word for N=50000 (50 KB LDS)

__device__ __forceinline__ int wave_incl_scan(int v, int lane) {
    #pragma unroll
    for (int d = 1; d < 64; d <<= 1) {
        int u = __shfl_up(v, d, 64);
        if (lane >= d) v += u;
    }
    return v;
}

// bf16 round-to-nearest-even (values finite; no NaN handling needed)
__device__ __forceinline__ unsigned bfr(float f) {
    unsigned u = __float_as_uint(f);
    return (u + 0x7FFFu + ((u >> 16) & 1u)) >> 16;
}
__device__ __forceinline__ unsigned packbf2(float lo, float hi) {
    return bfr(lo) | (bfr(hi) << 16);
}
__device__ __forceinline__ float bf2f(unsigned short h) {
    return __uint_as_float((unsigned)h << 16);
}

// ---------------- histogram: grid = (slice, which), u8 counts packed x4 ---
__global__ __launch_bounds__(256) void hist_kernel(
    const int* __restrict__ src, const int* __restrict__ dst,
    unsigned char* __restrict__ hist_o, unsigned char* __restrict__ hist_i,
    int E, int N)
{
    __shared__ unsigned int h[NMAXH4];
    int b = blockIdx.x, which = blockIdx.y, t = threadIdx.x;
    const int* col = which ? dst : src;
    int per = (E + NSLICE - 1) / NSLICE;
    int e0 = b * per, e1 = min(E, e0 + per);

    for (int j = t; j < NMAXH4; j += 256) h[j] = 0u;
    __syncthreads();

    int eV = e1 & ~3;
    const int4* c4 = (const int4*)col;
    for (int q = (e0 >> 2) + t; q < (eV >> 2); q += 256) {
        int4 v = c4[q];
        unsigned u;
        u = (unsigned)v.x; atomicAdd(&h[u >> 2], 1u << ((u & 3) * 8));
        u = (unsigned)v.y; atomicAdd(&h[u >> 2], 1u << ((u & 3) * 8));
        u = (unsigned)v.z; atomicAdd(&h[u >> 2], 1u << ((u & 3) * 8));
        u = (unsigned)v.w; atomicAdd(&h[u >> 2], 1u << ((u & 3) * 8));
    }
    for (int e = eV + t; e < e1; e += 256) {
        unsigned u = (unsigned)col[e];
        atomicAdd(&h[u >> 2], 1u << ((u & 3) * 8));
    }
    __syncthreads();

    // packed u32 writeout: word j holds counts for nodes 4j..4j+3
    unsigned* orow = (unsigned*)((which ? hist_i : hist_o) + (size_t)b * N);
    int nw = N >> 2;                     // 12500 for N=50000
    for (int j = t; j < nw; j += 256) orow[j] = h[j];
}

// ------ fused reduce + block-level scan + bf16 y = x*rs_odeg stream ------
__global__ __launch_bounds__(256) void reduce_scan_kernel(
    const unsigned char* __restrict__ hist_o, unsigned char* __restrict__ hist_i,
    int* __restrict__ offs, const float* __restrict__ x,
    unsigned short* __restrict__ y,
    float* __restrict__ rs_ideg, int* __restrict__ bsum, int N)
{
    int t = threadIdx.x, lane = t & 63, wid = t >> 6;
    int d = blockIdx.x * 256 + t;
    int run_o = 0, run_i = 0;
    if (d < N) {
        #pragma unroll 8
        for (int b = 0; b < NSLICE; ++b) {
            run_o += hist_o[(size_t)b * N + d];
            int tv = hist_i[(size_t)b * N + d];
            hist_i[(size_t)b * N + d] = (unsigned char)run_i;  // excl prefix over slices
            run_i += tv;
        }
    }
    int sv = wave_incl_scan(run_i, lane);
    __shared__ int ws[4], wso[4];
    __shared__ float sww[256];
    sww[t] = (d < N && run_o > 0) ? rsqrtf((float)run_o) : 0.0f;
    if (lane == 63) ws[wid] = sv;
    __syncthreads();
    if (t == 0) {
        int a = 0;
        for (int w = 0; w < 4; ++w) { wso[w] = a; a += ws[w]; }
        bsum[blockIdx.x] = a;
    }
    __syncthreads();
    if (d < N) {
        offs[d] = sv - run_i + wso[wid];
        rs_ideg[d] = (run_i > 0) ? rsqrtf((float)run_i) : 0.0f;
    }

    // coalesced y stream for rows [blockIdx*256, +256): w from LDS
    int r0 = blockIdx.x * 256;
    int nr = min(256, N - r0);
    if (nr <= 0) return;
    int tot = nr * 8;                     // uint4 chunks of 8 bf16
    for (int q = t; q < tot; q += 256) {
        int row = r0 + (q >> 3);
        int c8 = (q & 7) << 3;
        float w = sww[q >> 3];
        const float4 a = *(const float4*)&x[(size_t)row * DD + c8];
        const float4 b = *(const float4*)&x[(size_t)row * DD + c8 + 4];
        uint4 o;
        o.x = packbf2(a.x * w, a.y * w);
        o.y = packbf2(a.z * w, a.w * w);
        o.z = packbf2(b.x * w, b.y * w);
        o.w = packbf2(b.z * w, b.w * w);
        *(uint4*)&y[(size_t)row * DD + c8] = o;
    }
}

// ------ scan_add: offs += exclusive block prefix ------
__global__ __launch_bounds__(256) void scan_add_kernel(
    int* __restrict__ offs, const int* __restrict__ bsum, int n)
{
    __shared__ int wsum[4];
    int t = threadIdx.x, lane = t & 63, wid = t >> 6;
    int v = (t < blockIdx.x) ? bsum[t] : 0;    // nb <= 256
    #pragma unroll
    for (int dlt = 32; dlt >= 1; dlt >>= 1) v += __shfl_xor(v, dlt, 64);
    if (lane == 0) wsum[wid] = v;
    __syncthreads();
    int pre = wsum[0] + wsum[1] + wsum[2] + wsum[3];
    int i = blockIdx.x * 256 + t;
    if (i < n) offs[i] += pre;
}

// ---- bucket fill: LDS-segmented counting sort; SEG=16768, 3 segments ----
// Bracketed: global atomics = latency chain (60us); SEG=25000 = occupancy
// loss (159us total); SEG=16768/NSEG=3 = measured optimum (153.1us total).
#define SEG 16768
#define NSEG 3
__global__ __launch_bounds__(256) void bucket_kernel(
    const int* __restrict__ src, const int* __restrict__ dst,
    const int* __restrict__ offs, const unsigned char* __restrict__ hist_i,
    int* __restrict__ sorted_s, int E, int N)
{
    __shared__ int cur[SEG];
    int b = blockIdx.x, s = blockIdx.y, t = threadIdx.x;
    int per = (E + NSLICE - 1) / NSLICE;
    int e0 = b * per, e1 = min(E, e0 + per);
    int base = s * SEG;
    int segn = min(SEG, N - base);
    if (segn <= 0) return;

    for (int j = t; j < segn; j += 256)
        cur[j] = offs[base + j] + (int)hist_i[(size_t)b * N + base + j];
    __syncthreads();

    int eV = e1 & ~3;
    const int4* s4 = (const int4*)src;
    const int4* d4 = (const int4*)dst;
    for (int q = (e0 >> 2) + t; q < (eV >> 2); q += 256) {
        int4 dv = d4[q];
        int4 sv = s4[q];
        unsigned ux = (unsigned)(dv.x - base);
        unsigned uy = (unsigned)(dv.y - base);
        unsigned uz = (unsigned)(dv.z - base);
        unsigned uw = (unsigned)(dv.w - base);
        if (ux < (unsigned)segn) sorted_s[atomicAdd(&cur[ux], 1)] = sv.x;
        if (uy < (unsigned)segn) sorted_s[atomicAdd(&cur[uy], 1)] = sv.y;
        if (uz < (unsigned)segn) sorted_s[atomicAdd(&cur[uz], 1)] = sv.z;
        if (uw < (unsigned)segn) sorted_s[atomicAdd(&cur[uw], 1)] = sv.w;
    }
    for (int e = eV + t; e < e1; e += 256) {
        unsigned u = (unsigned)(dst[e] - base);
        if (u < (unsigned)segn)
            sorted_s[atomicAdd(&cur[u], 1)] = src[e];
    }
}

// macros for the pipelined gather (named scalars: no runtime-indexed arrays)
#define LDI8(A0,A1,A2,A3,A4,A5,A6,A7, base) \
    A0 = sorted_s[(base)+0]; A1 = sorted_s[(base)+1]; \
    A2 = sorted_s[(base)+2]; A3 = sorted_s[(base)+3]; \
    A4 = sorted_s[(base)+4]; A5 = sorted_s[(base)+5]; \
    A6 = sorted_s[(base)+6]; A7 = sorted_s[(base)+7];
#define LDR8(V0,V1,V2,V3,V4,V5,V6,V7, A0,A1,A2,A3,A4,A5,A6,A7) \
    V0 = *(const ushort4*)&y[(size_t)A0 * DD + coff]; \
    V1 = *(const ushort4*)&y[(size_t)A1 * DD + coff]; \
    V2 = *(const ushort4*)&y[(size_t)A2 * DD + coff]; \
    V3 = *(const ushort4*)&y[(size_t)A3 * DD + coff]; \
    V4 = *(const ushort4*)&y[(size_t)A4 * DD + coff]; \
    V5 = *(const ushort4*)&y[(size_t)A5 * DD + coff]; \
    V6 = *(const ushort4*)&y[(size_t)A6 * DD + coff]; \
    V7 = *(const ushort4*)&y[(size_t)A7 * DD + coff];
#define ACC1(V) \
    acc.x += bf2f(V.x); acc.y += bf2f(V.y); acc.z += bf2f(V.z); acc.w += bf2f(V.w);
#define ACC8(V0,V1,V2,V3,V4,V5,V6,V7) \
    ACC1(V0) ACC1(V1) ACC1(V2) ACC1(V3) ACC1(V4) ACC1(V5) ACC1(V6) ACC1(V7)

// ---- fused gather + FFN: 256 threads, 64 rows/block (grid 782), bf16 y ----
// 2-deep software pipeline + masked one-shot tail (round-13 measured best).
__global__ __launch_bounds__(256) void gather_ffn_kernel(
    const unsigned short* __restrict__ y,
    const int* __restrict__ sorted_s,
    const int* __restrict__ offs,
    const float* __restrict__ rs_ideg,
    const float* __restrict__ w1, const float* __restrict__ b1,
    const float* __restrict__ w2, const float* __restrict__ b2,
    float* __restrict__ out, int N, int E)
{
    __shared__ float sW[4096];          // W1 during GEMM1, W2 during GEMM2
    __shared__ float sT[64 * 68];

    int t = threadIdx.x;
    int row0 = blockIdx.x * 64;

    // stage W1 -> LDS; load W2 -> regs (written to LDS after GEMM1)
    const float4* w1v = (const float4*)w1;
    const float4* w2v = (const float4*)w2;
    float4 w2r[4];
    #pragma unroll
    for (int q = 0; q < 4; ++q) {
        ((float4*)sW)[t + q * 256] = w1v[t + q * 256];
        w2r[q] = w2v[t + q * 256];
    }

    // ---- gather phase: 16-lane subgroup per node, 4 nodes per subgroup ----
    int g = t >> 4, l16 = t & 15;
    int coff = l16 << 2;                // column index (4 cols = 8 B per lane)
    for (int r = g; r < 64; r += 16) {
        int d = row0 + r;
        float4 acc = make_float4(0.f, 0.f, 0.f, 0.f);
        if (d < N) {
            int beg = offs[d];
            int end = (d + 1 < N) ? offs[d + 1] : E;
            float nd = rs_ideg[d];
            int cnt = end - beg;
            int nch = cnt >> 3;

            int ia0, ia1, ia2, ia3, ia4, ia5, ia6, ia7;
            int ib0, ib1, ib2, ib3, ib4, ib5, ib6, ib7;
            ushort4 va0, va1, va2, va3, va4, va5, va6, va7;
            ushort4 vb0, vb1, vb2, vb3, vb4, vb5, vb6, vb7;

            if (nch > 0) {
                LDI8(ia0,ia1,ia2,ia3,ia4,ia5,ia6,ia7, beg)
                LDR8(va0,va1,va2,va3,va4,va5,va6,va7, ia0,ia1,ia2,ia3,ia4,ia5,ia6,ia7)
                if (nch > 1) { LDI8(ib0,ib1,ib2,ib3,ib4,ib5,ib6,ib7, beg + 8) }
                int c = 0, k = beg;
                for (; c + 2 <= nch; c += 2) {
                    // rows of chunk c+1 (younger than va's loads)
                    LDR8(vb0,vb1,vb2,vb3,vb4,vb5,vb6,vb7, ib0,ib1,ib2,ib3,ib4,ib5,ib6,ib7)
                    if (c + 2 < nch) { LDI8(ia0,ia1,ia2,ia3,ia4,ia5,ia6,ia7, k + 16) }
                    ACC8(va0,va1,va2,va3,va4,va5,va6,va7)   // waits on va only
                    k += 8;
                    if (c + 2 < nch) {
                        LDR8(va0,va1,va2,va3,va4,va5,va6,va7, ia0,ia1,ia2,ia3,ia4,ia5,ia6,ia7)
                        if (c + 3 < nch) { LDI8(ib0,ib1,ib2,ib3,ib4,ib5,ib6,ib7, k + 16) }
                    }
                    ACC8(vb0,vb1,vb2,vb3,vb4,vb5,vb6,vb7)
                    k += 8;
                }
                if (c < nch) {          // odd chunk count: last chunk sits in va
                    ACC8(va0,va1,va2,va3,va4,va5,va6,va7)
                }
            }
            // masked one-shot tail: rr in [0,7]
            int kt = beg + (nch << 3);
            int rr = end - kt;
            if (rr > 0) {
                int lastv = rr - 1;
                int t0 = sorted_s[kt];
                int t1 = sorted_s[kt + ((1 < rr) ? 1 : lastv)];
                int t2 = sorted_s[kt + ((2 < rr) ? 2 : lastv)];
                int t3 = sorted_s[kt + ((3 < rr) ? 3 : lastv)];
                int t4 = sorted_s[kt + ((4 < rr) ? 4 : lastv)];
                int t5 = sorted_s[kt + ((5 < rr) ? 5 : lastv)];
                int t6 = sorted_s[kt + ((6 < rr) ? 6 : lastv)];
                int t7 = sorted_s[kt + ((7 < rr) ? 7 : lastv)];
                ushort4 w0, w1q, w2q, w3, w4, w5, w6, w7;
                LDR8(w0,w1q,w2q,w3,w4,w5,w6,w7, t0,t1,t2,t3,t4,t5,t6,t7)
                ACC1(w0)                                     // j=0 always valid
                acc.x += (1 < rr) ? bf2f(w1q.x) : 0.0f; acc.y += (1 < rr) ? bf2f(w1q.y) : 0.0f;
                acc.z += (1 < rr) ? bf2f(w1q.z) : 0.0f; acc.w += (1 < rr) ? bf2f(w1q.w) : 0.0f;
                acc.x += (2 < rr) ? bf2f(w2q.x) : 0.0f; acc.y += (2 < rr) ? bf2f(w2q.y) : 0.0f;
                acc.z += (2 < rr) ? bf2f(w2q.z) : 0.0f; acc.w += (2 < rr) ? bf2f(w2q.w) : 0.0f;
                acc.x += (3 < rr) ? bf2f(w3.x) : 0.0f; acc.y += (3 < rr) ? bf2f(w3.y) : 0.0f;
                acc.z += (3 < rr) ? bf2f(w3.z) : 0.0f; acc.w += (3 < rr) ? bf2f(w3.w) : 0.0f;
                acc.x += (4 < rr) ? bf2f(w4.x) : 0.0f; acc.y += (4 < rr) ? bf2f(w4.y) : 0.0f;
                acc.z += (4 < rr) ? bf2f(w4.z) : 0.0f; acc.w += (4 < rr) ? bf2f(w4.w) : 0.0f;
                acc.x += (5 < rr) ? bf2f(w5.x) : 0.0f; acc.y += (5 < rr) ? bf2f(w5.y) : 0.0f;
                acc.z += (5 < rr) ? bf2f(w5.z) : 0.0f; acc.w += (5 < rr) ? bf2f(w5.w) : 0.0f;
                acc.x += (6 < rr) ? bf2f(w6.x) : 0.0f; acc.y += (6 < rr) ? bf2f(w6.y) : 0.0f;
                acc.z += (6 < rr) ? bf2f(w6.z) : 0.0f; acc.w += (6 < rr) ? bf2f(w6.w) : 0.0f;
                acc.x += (7 < rr) ? bf2f(w7.x) : 0.0f; acc.y += (7 < rr) ? bf2f(w7.y) : 0.0f;
                acc.z += (7 < rr) ? bf2f(w7.z) : 0.0f; acc.w += (7 < rr) ? bf2f(w7.w) : 0.0f;
            }
            acc.x *= nd; acc.y *= nd; acc.z *= nd; acc.w *= nd;
        }
        *(float4*)&sT[r * 68 + coff] = acc;
    }
    __syncthreads();

    // ---- FFN phase: slot = t>>3 (0..31) covers rows slot, slot+32 ----
    int slot = t >> 3;
    int cb = (t & 7) << 3;

    float a[2][8];
    #pragma unroll
    for (int j = 0; j < 8; ++j) {
        float bv = b1[cb + j];
        a[0][j] = bv; a[1][j] = bv;
    }
    #pragma unroll 2
    for (int k = 0; k < 64; ++k) {
        float rv0 = sT[(slot      ) * 68 + k];
        float rv1 = sT[(slot + 32 ) * 68 + k];
        #pragma unroll
        for (int q = 0; q < 2; ++q) {
            float4 w = *(const float4*)&sW[k * 64 + cb + (q << 2)];
            a[0][q*4+0] = fmaf(rv0, w.x, a[0][q*4+0]); a[1][q*4+0] = fmaf(rv1, w.x, a[1][q*4+0]);
            a[0][q*4+1] = fmaf(rv0, w.y, a[0][q*4+1]); a[1][q*4+1] = fmaf(rv1, w.y, a[1][q*4+1]);
            a[0][q*4+2] = fmaf(rv0, w.z, a[0][q*4+2]); a[1][q*4+2] = fmaf(rv1, w.z, a[1][q*4+2]);
            a[0][q*4+3] = fmaf(rv0, w.w, a[0][q*4+3]); a[1][q*4+3] = fmaf(rv1, w.w, a[1][q*4+3]);
        }
    }
    #pragma unroll
    for (int i = 0; i < 2; ++i)
        #pragma unroll
        for (int j = 0; j < 8; ++j) {
            float v = a[i][j];
            a[i][j] = 0.5f * v * (1.0f + erff(v * 0.70710678118654752f));
        }
    __syncthreads();   // all GEMM1 reads of sT AND sW complete before overwrite
    #pragma unroll
    for (int i = 0; i < 2; ++i)
        #pragma unroll
        for (int q = 0; q < 2; ++q)
            *(float4*)&sT[(slot + 32 * i) * 68 + cb + (q << 2)] =
                make_float4(a[i][q*4+0], a[i][q*4+1], a[i][q*4+2], a[i][q*4+3]);
    #pragma unroll
    for (int q = 0; q < 4; ++q)
        ((float4*)sW)[t + q * 256] = w2r[q];     // W2 into the shared buffer
    __syncthreads();

    float o[2][8];
    #pragma unroll
    for (int j = 0; j < 8; ++j) {
        float bv = b2[cb + j];
        o[0][j] = bv; o[1][j] = bv;
    }
    #pragma unroll 2
    for (int k = 0; k < 64; ++k) {
        float hv0 = sT[(slot      ) * 68 + k];
        float hv1 = sT[(slot + 32 ) * 68 + k];
        #pragma unroll
        for (int q = 0; q < 2; ++q) {
            float4 w = *(const float4*)&sW[k * 64 + cb + (q << 2)];
            o[0][q*4+0] = fmaf(hv0, w.x, o[0][q*4+0]); o[1][q*4+0] = fmaf(hv1, w.x, o[1][q*4+0]);
            o[0][q*4+1] = fmaf(hv0, w.y, o[0][q*4+1]); o[1][q*4+1] = fmaf(hv1, w.y, o[1][q*4+1]);
            o[0][q*4+2] = fmaf(hv0, w.z, o[0][q*4+2]); o[1][q*4+2] = fmaf(hv1, w.z, o[1][q*4+2]);
            o[0][q*4+3] = fmaf(hv0, w.w, o[0][q*4+3]); o[1][q*4+3] = fmaf(hv1, w.w, o[1][q*4+3]);
        }
    }
    // direct store: thread covers rows slot, slot+32, cols cb..cb+7
    #pragma unroll
    for (int i = 0; i < 2; ++i) {
        int row = row0 + slot + 32 * i;
        if (row < N) {
            *(float4*)&out[(size_t)row * DD + cb    ] =
                make_float4(o[i][0], o[i][1], o[i][2], o[i][3]);
            *(float4*)&out[(size_t)row * DD + cb + 4] =
                make_float4(o[i][4], o[i][5], o[i][6], o[i][7]);
        }
    }
}

extern "C" void kernel_launch(void* const* d_in, const int* in_sizes, int n_in,
                              void* d_out, int out_size, void* d_ws, size_t ws_size,
                              hipStream_t stream)
{
    const float* x    = (const float*)d_in[0];
    const int*   esrc = (const int*)d_in[1];
    const int*   edst = (const int*)d_in[2];
    const float* w1   = (const float*)d_in[3];
    const float* b1   = (const float*)d_in[4];
    const float* w2   = (const float*)d_in[5];
    const float* b2   = (const float*)d_in[6];
    float* out = (float*)d_out;

    int N = in_sizes[0] / DD;   // 50000
    int E = in_sizes[1];        // 800000
    int nb = (N + 255) / 256;   // 196

    // workspace layout (d_ws is >=256B aligned)
    unsigned short* y          = (unsigned short*)d_ws;              // N*DD bf16
    int*            sorted_s   = (int*)(y + (size_t)N * DD);         // E
    int*            offs       = sorted_s + E;                       // N
    float*          rs_ideg    = (float*)(offs + N);                 // N
    int*            bsum       = (int*)(rs_ideg + N);                // 256
    unsigned char*  hist_o     = (unsigned char*)(bsum + 256);       // NSLICE*N u8
    unsigned char*  hist_i     = hist_o + (size_t)NSLICE * N;        // NSLICE*N u8

    hist_kernel<<<dim3(NSLICE, 2), 256, 0, stream>>>(esrc, edst, hist_o, hist_i, E, N);
    reduce_scan_kernel<<<nb, 256, 0, stream>>>(hist_o, hist_i, offs, x, y, rs_ideg, bsum, N);
    scan_add_kernel<<<nb, 256, 0, stream>>>(offs, bsum, N);
    bucket_kernel<<<dim3(NSLICE, NSEG), 256, 0, stream>>>(esrc, edst, offs, hist_i, sorted_s, E, N);
    gather_ffn_kernel<<<(N + 63) / 64, 256, 0, stream>>>(y, sorted_s, offs, rs_ideg,
                                                         w1, b1, w2, b2, out, N, E);
}